// Round 1
// baseline (1850.185 us; speedup 1.0000x reference)
//
#include <hip/hip_runtime.h>

#define W_  240
#define H_  128
#define C_  256
#define N_  2
#define HW_ (H_*W_)

// One thread per (n, s in [0,18), h, w).
//  s in [0,9)  -> corr_att_offset output (search position s)
//  s in [9,18) -> corr_iter output (3x3 shift j = s-9)
// Each thread computes the 4 bilinear tap offsets/weights once, then loops
// over 256 channels (4 groups of 64) accumulating f1*bilinear(f2).
__global__ __launch_bounds__(256) void corr_kernel(
    const float* __restrict__ fmap1, const float* __restrict__ fmap2,
    const float* __restrict__ flow,  const float* __restrict__ eo,
    float* __restrict__ out0, float* __restrict__ out1)
{
    int t = blockIdx.x * 256 + threadIdx.x;
    int w = t % W_;
    int tmp = t / W_;
    int h = tmp % H_;
    tmp /= H_;
    int s = tmp % 18;
    int n = tmp / 18;

    float x, y;
    float* outp;
    if (s < 9) {
        int pix = h * W_ + w;
        float fx = flow[((size_t)n*2 + 0)*HW_ + pix];
        float fy = flow[((size_t)n*2 + 1)*HW_ + pix];
        float ex = eo[((size_t)n*18 + 2*s    )*HW_ + pix];
        float ey = eo[((size_t)n*18 + 2*s + 1)*HW_ + pix];
        x = (float)w + fx + (float)(s - 4) + ex;
        y = (float)h + fy + ey;
        outp = out0 + ((size_t)n*36 + s)*HW_ + pix;
    } else {
        int j = s - 9;
        int dy = j / 3 - 1, dx = j % 3 - 1;
        int hh = min(max(h + dy, 0), H_ - 1);
        int ww = min(max(w + dx, 0), W_ - 1);
        int pix2 = hh * W_ + ww;
        float fx = flow[((size_t)n*2 + 0)*HW_ + pix2];
        float fy = flow[((size_t)n*2 + 1)*HW_ + pix2];
        x = (float)ww + fx;
        y = (float)hh + fy;
        outp = out1 + ((size_t)n*36 + j)*HW_ + h*W_ + w;
    }

    // Bilinear taps: validity tested on UNclamped coords (zero-pad semantics),
    // load from clamped index (safe).
    float x0 = floorf(x), y0 = floorf(y);
    float fx1 = x - x0, fy1 = y - y0;
    float fx0 = 1.f - fx1, fy0 = 1.f - fy1;

    int   offs[4];
    float wts[4];
    #pragma unroll
    for (int b = 0; b < 2; ++b) {
        #pragma unroll
        for (int a = 0; a < 2; ++a) {
            float xi = x0 + (float)a;
            float yi = y0 + (float)b;
            bool valid = (xi >= 0.f) & (xi <= (float)(W_ - 1)) &
                         (yi >= 0.f) & (yi <= (float)(H_ - 1));
            float xc = fminf(fmaxf(xi, 0.f), (float)(W_ - 1));
            float yc = fminf(fmaxf(yi, 0.f), (float)(H_ - 1));
            offs[b*2 + a] = (int)yc * W_ + (int)xc;
            wts [b*2 + a] = (valid ? 1.f : 0.f) * (a ? fx1 : fx0) * (b ? fy1 : fy0);
        }
    }

    const float* f1p = fmap1 + (size_t)n*C_*HW_ + h*W_ + w;
    const float* f2p = fmap2 + (size_t)n*C_*HW_;

    float acc[4] = {0.f, 0.f, 0.f, 0.f};
    for (int c = 0; c < 64; ++c) {
        #pragma unroll
        for (int g = 0; g < 4; ++g) {
            int cc = g*64 + c;
            float f1 = f1p[(size_t)cc*HW_];
            const float* p2 = f2p + (size_t)cc*HW_;
            float smp = wts[0]*p2[offs[0]] + wts[1]*p2[offs[1]]
                      + wts[2]*p2[offs[2]] + wts[3]*p2[offs[3]];
            acc[g] = fmaf(f1, smp, acc[g]);
        }
    }

    #pragma unroll
    for (int g = 0; g < 4; ++g)
        outp[(size_t)g*9*HW_] = acc[g] * (1.f/64.f);
}

// One thread per (n, rc in [0,16), h, w). rc = r*4 + c subpixel.
// flow_up[n,ch,4h+r,4w+c] = -sum_j softmax_j(mask[n, j*16+rc, h, w]) * 4*flow_pad[n,ch,h+dy-1,w+dx-1]
__global__ __launch_bounds__(256) void upsample_kernel(
    const float* __restrict__ flow, const float* __restrict__ mask,
    float* __restrict__ out2)
{
    int t = blockIdx.x * 256 + threadIdx.x;
    int w = t % W_;
    int tmp = t / W_;
    int h = tmp % H_;
    tmp /= H_;
    int rc = tmp % 16;
    int n  = tmp / 16;
    int pix = h * W_ + w;

    const float* mp = mask + ((size_t)n*144 + rc)*HW_ + pix;
    float mv[9];
    float mx = -1e30f;
    #pragma unroll
    for (int j = 0; j < 9; ++j) {
        mv[j] = mp[(size_t)(j*16)*HW_];
        mx = fmaxf(mx, mv[j]);
    }
    float ssum = 0.f;
    #pragma unroll
    for (int j = 0; j < 9; ++j) {
        mv[j] = __expf(mv[j] - mx);
        ssum += mv[j];
    }
    float inv = 1.f / ssum;

    float a0 = 0.f, a1 = 0.f;
    #pragma unroll
    for (int j = 0; j < 9; ++j) {
        int dy = j / 3 - 1, dx = j % 3 - 1;
        int hh = h + dy, ww = w + dx;
        bool ok = (hh >= 0) & (hh < H_) & (ww >= 0) & (ww < W_);
        float f0 = 0.f, f1v = 0.f;
        if (ok) {
            int p2 = hh * W_ + ww;
            f0  = flow[((size_t)n*2 + 0)*HW_ + p2];
            f1v = flow[((size_t)n*2 + 1)*HW_ + p2];
        }
        a0 = fmaf(mv[j], f0,  a0);
        a1 = fmaf(mv[j], f1v, a1);
    }

    int r = rc >> 2, c = rc & 3;
    float scale = -4.f * inv;
    size_t up_hw = (size_t)(4*H_) * (4*W_);
    size_t o = (size_t)(n*2) * up_hw + (size_t)(4*h + r) * (4*W_) + (4*w + c);
    out2[o]         = a0 * scale;
    out2[o + up_hw] = a1 * scale;
}

extern "C" void kernel_launch(void* const* d_in, const int* in_sizes, int n_in,
                              void* d_out, int out_size, void* d_ws, size_t ws_size,
                              hipStream_t stream) {
    const float* fmap1 = (const float*)d_in[0];
    const float* fmap2 = (const float*)d_in[1];
    const float* flow  = (const float*)d_in[2];
    const float* eo    = (const float*)d_in[3];
    const float* mask  = (const float*)d_in[4];

    float* out  = (float*)d_out;
    float* out0 = out;                            // (N,36,H,W) corr_att_offset
    float* out1 = out + (size_t)N_*36*HW_;        // (N,36,H,W) corr_iter
    float* out2 = out + (size_t)2*N_*36*HW_;      // (N,2,4H,4W) flow_up

    corr_kernel<<<(N_*18*HW_)/256, 256, 0, stream>>>(fmap1, fmap2, flow, eo, out0, out1);
    upsample_kernel<<<(N_*16*HW_)/256, 256, 0, stream>>>(flow, mask, out2);
}

// Round 2
// 1237.382 us; speedup vs baseline: 1.4952x; 1.4952x over previous
//
#include <hip/hip_runtime.h>

#define W_   240
#define H_   128
#define C_   256
#define N_   2
#define HW_  (H_*W_)      // 30720
#define UPW_ (4*W_)       // 960
#define UPHW_ ((size_t)(4*H_)*(4*W_))

// Block = (n, group g, 16x8 tile). 128 threads, one pixel each.
// Thread preloads its 64 fmap1 channels to registers, then loops s=0..17:
//   s in [0,9)  -> corr_att_offset (search position s)
//   s in [9,18) -> corr_iter (3x3 shift j = s-9)
// computing taps per-s and a 64-channel gather-dot against fmap2.
__global__ __launch_bounds__(128) void corr_kernel(
    const float* __restrict__ fmap1, const float* __restrict__ fmap2,
    const float* __restrict__ flow,  const float* __restrict__ eo,
    float* __restrict__ out0, float* __restrict__ out1)
{
    // XCD swizzle: 1920 blocks, 8 XCDs, 240 blocks/chunk = one (n,g) slice,
    // row-major tile order within the chunk (L2 sliding window).
    int bid = blockIdx.x;
    int b   = (bid & 7) * 240 + (bid >> 3);
    int tx = b % 15;  b /= 15;
    int ty = b % 16;  b /= 16;
    int g  = b & 3;
    int n  = b >> 2;

    int lx = threadIdx.x & 15;
    int ly = threadIdx.x >> 4;
    int w  = tx * 16 + lx;
    int h  = ty * 8  + ly;
    int pix = h * W_ + w;

    const float* f1p = fmap1 + ((size_t)(n*4 + g) * 64) * HW_ + pix;
    const float* f2g = fmap2 + ((size_t)(n*4 + g) * 64) * HW_;

    float fx = flow[((size_t)n*2 + 0)*HW_ + pix];
    float fy = flow[((size_t)n*2 + 1)*HW_ + pix];

    // Preload 64 fmap1 channels (reused by all 18 s-values).
    float f1c[64];
    #pragma unroll
    for (int c = 0; c < 64; ++c)
        f1c[c] = f1p[(size_t)c * HW_];

    float* o0base = out0 + ((size_t)(n*36 + g*9))*HW_ + pix;
    float* o1base = out1 + ((size_t)(n*36 + g*9))*HW_ + pix;

    for (int s = 0; s < 18; ++s) {
        float x, y;
        float* outp;
        if (s < 9) {
            float ex = eo[((size_t)n*18 + 2*s    )*HW_ + pix];
            float ey = eo[((size_t)n*18 + 2*s + 1)*HW_ + pix];
            x = (float)w + fx + (float)(s - 4) + ex;
            y = (float)h + fy + ey;
            outp = o0base + (size_t)s * HW_;
        } else {
            int j  = s - 9;
            int dy = j / 3 - 1, dx = j % 3 - 1;
            int hh = min(max(h + dy, 0), H_ - 1);
            int ww = min(max(w + dx, 0), W_ - 1);
            int p2 = hh * W_ + ww;
            float nfx = flow[((size_t)n*2 + 0)*HW_ + p2];
            float nfy = flow[((size_t)n*2 + 1)*HW_ + p2];
            x = (float)ww + nfx;
            y = (float)hh + nfy;
            outp = o1base + (size_t)j * HW_;
        }

        // Bilinear taps: validity on UNclamped coords, load from clamped idx.
        float x0 = floorf(x), y0 = floorf(y);
        float fx1 = x - x0, fy1 = y - y0;
        float fx0 = 1.f - fx1, fy0 = 1.f - fy1;

        int   offs[4];
        float wts[4];
        #pragma unroll
        for (int bb = 0; bb < 2; ++bb) {
            #pragma unroll
            for (int aa = 0; aa < 2; ++aa) {
                float xi = x0 + (float)aa;
                float yi = y0 + (float)bb;
                bool valid = (xi >= 0.f) & (xi <= (float)(W_ - 1)) &
                             (yi >= 0.f) & (yi <= (float)(H_ - 1));
                float xc = fminf(fmaxf(xi, 0.f), (float)(W_ - 1));
                float yc = fminf(fmaxf(yi, 0.f), (float)(H_ - 1));
                offs[bb*2 + aa] = (int)yc * W_ + (int)xc;
                wts [bb*2 + aa] = (valid ? 1.f : 0.f) * (aa ? fx1 : fx0) * (bb ? fy1 : fy0);
            }
        }

        const float* p0 = f2g + offs[0];
        const float* p1 = f2g + offs[1];
        const float* p2p = f2g + offs[2];
        const float* p3 = f2g + offs[3];
        float w0 = wts[0], w1 = wts[1], w2 = wts[2], w3 = wts[3];

        float acc = 0.f;
        #pragma unroll
        for (int c = 0; c < 64; ++c) {
            size_t co = (size_t)c * HW_;
            float smp = w0*p0[co] + w1*p1[co] + w2*p2p[co] + w3*p3[co];
            acc = fmaf(f1c[c], smp, acc);
        }
        *outp = acc * (1.f/64.f);
    }
}

// One thread per input pixel (n,h,w); computes all 16 sub-pixels.
// flow taps loaded once (9x2), mask read 144x coalesced, stores as float4.
__global__ __launch_bounds__(256) void upsample_kernel(
    const float* __restrict__ flow, const float* __restrict__ mask,
    float* __restrict__ out2)
{
    int t = blockIdx.x * 256 + threadIdx.x;
    int w = t % W_;
    int tmp = t / W_;
    int h = tmp % H_;
    int n = tmp / H_;
    int pix = h * W_ + w;

    // Preload 9 zero-padded flow taps x 2 channels, pre-scaled by -4.
    float ft0[9], ft1[9];
    #pragma unroll
    for (int j = 0; j < 9; ++j) {
        int dy = j / 3 - 1, dx = j % 3 - 1;
        int hh = h + dy, ww = w + dx;
        bool ok = (hh >= 0) & (hh < H_) & (ww >= 0) & (ww < W_);
        float f0 = 0.f, f1v = 0.f;
        if (ok) {
            int p2 = hh * W_ + ww;
            f0  = flow[((size_t)n*2 + 0)*HW_ + p2];
            f1v = flow[((size_t)n*2 + 1)*HW_ + p2];
        }
        ft0[j] = -4.f * f0;
        ft1[j] = -4.f * f1v;
    }

    float a0[16], a1[16];
    #pragma unroll
    for (int rc = 0; rc < 16; ++rc) {
        const float* mp = mask + ((size_t)n*144 + rc)*HW_ + pix;
        float mv[9];
        float mx = -1e30f;
        #pragma unroll
        for (int j = 0; j < 9; ++j) {
            mv[j] = mp[(size_t)(j*16)*HW_];
            mx = fmaxf(mx, mv[j]);
        }
        float ssum = 0.f;
        #pragma unroll
        for (int j = 0; j < 9; ++j) {
            mv[j] = __expf(mv[j] - mx);
            ssum += mv[j];
        }
        float inv = 1.f / ssum;
        float s0 = 0.f, s1 = 0.f;
        #pragma unroll
        for (int j = 0; j < 9; ++j) {
            s0 = fmaf(mv[j], ft0[j], s0);
            s1 = fmaf(mv[j], ft1[j], s1);
        }
        a0[rc] = s0 * inv;
        a1[rc] = s1 * inv;
    }

    float* ob = out2 + (size_t)(n*2) * UPHW_ + (size_t)(4*h) * UPW_ + 4*w;
    #pragma unroll
    for (int r = 0; r < 4; ++r) {
        float4 v0 = make_float4(a0[r*4+0], a0[r*4+1], a0[r*4+2], a0[r*4+3]);
        float4 v1 = make_float4(a1[r*4+0], a1[r*4+1], a1[r*4+2], a1[r*4+3]);
        *reinterpret_cast<float4*>(ob + (size_t)r * UPW_)          = v0;
        *reinterpret_cast<float4*>(ob + (size_t)r * UPW_ + UPHW_)  = v1;
    }
}

extern "C" void kernel_launch(void* const* d_in, const int* in_sizes, int n_in,
                              void* d_out, int out_size, void* d_ws, size_t ws_size,
                              hipStream_t stream) {
    const float* fmap1 = (const float*)d_in[0];
    const float* fmap2 = (const float*)d_in[1];
    const float* flow  = (const float*)d_in[2];
    const float* eo    = (const float*)d_in[3];
    const float* mask  = (const float*)d_in[4];

    float* out  = (float*)d_out;
    float* out0 = out;                            // (N,36,H,W) corr_att_offset
    float* out1 = out + (size_t)N_*36*HW_;        // (N,36,H,W) corr_iter
    float* out2 = out + (size_t)2*N_*36*HW_;      // (N,2,4H,4W) flow_up

    // corr: 2 n * 4 g * 16 ty * 15 tx = 1920 blocks of 128 threads
    corr_kernel<<<1920, 128, 0, stream>>>(fmap1, fmap2, flow, eo, out0, out1);
    // upsample: 2*128*240 / 256 = 240 blocks
    upsample_kernel<<<240, 256, 0, stream>>>(flow, mask, out2);
}

// Round 4
// 733.424 us; speedup vs baseline: 2.5227x; 1.6871x over previous
//
#include <hip/hip_runtime.h>

#define N_    2
#define W_    240
#define H_    128
#define HW_   (H_*W_)       // 30720
#define UPW_  (4*W_)        // 960
#define UPHW_ ((size_t)(4*H_)*(4*W_))

#define TS    16            // 16x16 pixel tile per block
#define HALO  13
#define WIN   43            // TS + 2*HALO + 1
#define WIN2  (WIN*WIN)     // 1849
#define CH    4             // channels staged per chunk
#define NCHUNK (64/CH)      // 16

// Block = (n,g, 16x16 tile), 256 threads (1 pixel each).
// Stage fmap2 window (43x43 x CH ch) in LDS; precompute all 18 sample coords;
// accumulate 18 bilinear-dot outputs from LDS (global fallback for outlier flow).
__global__ __launch_bounds__(256, 4) void corr_kernel(
    const float* __restrict__ fmap1, const float* __restrict__ fmap2,
    const float* __restrict__ flow,  const float* __restrict__ eo,
    float* __restrict__ out0, float* __restrict__ out1)
{
    __shared__ float win[CH*WIN2];   // 29584 B

    // XCD swizzle: slice (n,g) = bid&7 -> each XCD works one 64-ch slice,
    // tiles in row-major order (L2 sliding window per XCD).
    int bid   = blockIdx.x;
    int slice = bid & 7;
    int t     = bid >> 3;            // 0..119
    int tx = t % 15, ty = t / 15;
    int n = slice >> 2, g = slice & 3;

    int lx = threadIdx.x & 15, ly = threadIdx.x >> 4;
    int w = tx*TS + lx, h = ty*TS + ly;
    int pix = h*W_ + w;
    int wx0 = tx*TS - HALO, wy0 = ty*TS - HALO;

    const float* f2g = fmap2 + (size_t)(slice*64)*HW_;
    const float* f1p = fmap1 + (size_t)(slice*64)*HW_ + pix;

    float fx = flow[((size_t)n*2 + 0)*HW_ + pix];
    float fy = flow[((size_t)n*2 + 1)*HW_ + pix];

    // Precompute all 18 sample coordinates (chunk-invariant).
    float xs[18], ys[18];
    #pragma unroll
    for (int s = 0; s < 9; ++s) {
        float ex = eo[((size_t)n*18 + 2*s    )*HW_ + pix];
        float ey = eo[((size_t)n*18 + 2*s + 1)*HW_ + pix];
        xs[s] = (float)w + fx + (float)(s - 4) + ex;
        ys[s] = (float)h + fy + ey;
    }
    #pragma unroll
    for (int j = 0; j < 9; ++j) {
        int dy = j/3 - 1, dx = j%3 - 1;
        int hh = min(max(h + dy, 0), H_-1);
        int ww = min(max(w + dx, 0), W_-1);
        int p2 = hh*W_ + ww;
        xs[9+j] = (float)ww + flow[((size_t)n*2 + 0)*HW_ + p2];
        ys[9+j] = (float)hh + flow[((size_t)n*2 + 1)*HW_ + p2];
    }

    float acc[18];
    #pragma unroll
    for (int s = 0; s < 18; ++s) acc[s] = 0.f;

    for (int ck = 0; ck < NCHUNK; ++ck) {
        int c0 = ck*CH;
        __syncthreads();
        // Stage window for CH channels (edge-clamped source).
        for (int it = threadIdx.x; it < CH*WIN2; it += 256) {
            int ch  = it / WIN2;
            int rem = it - ch*WIN2;
            int r   = rem / WIN;
            int c   = rem - r*WIN;
            int gy = min(max(wy0 + r, 0), H_-1);
            int gx = min(max(wx0 + c, 0), W_-1);
            win[it] = f2g[(size_t)(c0+ch)*HW_ + gy*W_ + gx];
        }
        __syncthreads();

        float f1v[CH];
        #pragma unroll
        for (int ci = 0; ci < CH; ++ci) f1v[ci] = f1p[(size_t)(c0+ci)*HW_];

        #pragma unroll
        for (int s = 0; s < 18; ++s) {
            float x = xs[s], y = ys[s];
            float x0f = floorf(x), y0f = floorf(y);
            float fx1 = x - x0f, fy1 = y - y0f;
            float fx0 = 1.f - fx1, fy0 = 1.f - fy1;
            int ix0 = (int)x0f, iy0 = (int)y0f;
            int ix0c = min(max(ix0,   0), W_-1), ix1c = min(max(ix0+1, 0), W_-1);
            int iy0c = min(max(iy0,   0), H_-1), iy1c = min(max(iy0+1, 0), H_-1);
            float vx0 = (ix0   >= 0 && ix0   <= W_-1) ? fx0 : 0.f;
            float vx1 = (ix0+1 >= 0 && ix0+1 <= W_-1) ? fx1 : 0.f;
            float vy0 = (iy0   >= 0 && iy0   <= H_-1) ? fy0 : 0.f;
            float vy1 = (iy0+1 >= 0 && iy0+1 <= H_-1) ? fy1 : 0.f;
            float w00 = vy0*vx0, w01 = vy0*vx1, w10 = vy1*vx0, w11 = vy1*vx1;
            int cx0 = ix0c - wx0, cx1 = ix1c - wx0;
            int cy0 = iy0c - wy0, cy1 = iy1c - wy0;
            bool allin = ((unsigned)cx0 < WIN) & ((unsigned)cx1 < WIN) &
                         ((unsigned)cy0 < WIN) & ((unsigned)cy1 < WIN);
            float a = 0.f;
            if (allin) {
                int o00 = cy0*WIN + cx0, o01 = cy0*WIN + cx1;
                int o10 = cy1*WIN + cx0, o11 = cy1*WIN + cx1;
                #pragma unroll
                for (int ci = 0; ci < CH; ++ci) {
                    const float* wp = win + ci*WIN2;
                    float smp = w00*wp[o00] + w01*wp[o01]
                              + w10*wp[o10] + w11*wp[o11];
                    a = fmaf(f1v[ci], smp, a);
                }
            } else {
                int g00 = iy0c*W_ + ix0c, g01 = iy0c*W_ + ix1c;
                int g10 = iy1c*W_ + ix0c, g11 = iy1c*W_ + ix1c;
                #pragma unroll
                for (int ci = 0; ci < CH; ++ci) {
                    const float* gp = f2g + (size_t)(c0+ci)*HW_;
                    float smp = w00*gp[g00] + w01*gp[g01]
                              + w10*gp[g10] + w11*gp[g11];
                    a = fmaf(f1v[ci], smp, a);
                }
            }
            acc[s] += a;
        }
    }

    float* o0 = out0 + ((size_t)(n*36 + g*9))*HW_ + pix;
    float* o1 = out1 + ((size_t)(n*36 + g*9))*HW_ + pix;
    #pragma unroll
    for (int s = 0; s < 9; ++s) o0[(size_t)s*HW_] = acc[s]   * (1.f/64.f);
    #pragma unroll
    for (int j = 0; j < 9; ++j) o1[(size_t)j*HW_] = acc[9+j] * (1.f/64.f);
}

// Thread per (n, r, h, w): computes 4 horizontal sub-pixels (c=0..3),
// stores one contiguous float4 per output channel.
__global__ __launch_bounds__(256) void upsample_kernel(
    const float* __restrict__ flow, const float* __restrict__ mask,
    float* __restrict__ out2)
{
    int t = blockIdx.x * 256 + threadIdx.x;
    int w = t % W_;
    int tmp = t / W_;
    int h = tmp % H_;
    tmp /= H_;
    int r = tmp & 3;
    int n = tmp >> 2;
    int pix = h * W_ + w;

    float ft0[9], ft1[9];
    #pragma unroll
    for (int j = 0; j < 9; ++j) {
        int dy = j/3 - 1, dx = j%3 - 1;
        int hh = h + dy, ww = w + dx;
        bool ok = (hh >= 0) & (hh < H_) & (ww >= 0) & (ww < W_);
        float f0 = 0.f, f1v = 0.f;
        if (ok) {
            int p2 = hh * W_ + ww;
            f0  = flow[((size_t)n*2 + 0)*HW_ + p2];
            f1v = flow[((size_t)n*2 + 1)*HW_ + p2];
        }
        ft0[j] = -4.f * f0;
        ft1[j] = -4.f * f1v;
    }

    float a0[4], a1[4];
    #pragma unroll
    for (int c = 0; c < 4; ++c) {
        const float* mp = mask + ((size_t)n*144 + r*4 + c)*HW_ + pix;
        float mv[9];
        float mx = -1e30f;
        #pragma unroll
        for (int j = 0; j < 9; ++j) {
            mv[j] = mp[(size_t)(j*16)*HW_];
            mx = fmaxf(mx, mv[j]);
        }
        float ssum = 0.f;
        #pragma unroll
        for (int j = 0; j < 9; ++j) {
            mv[j] = __expf(mv[j] - mx);
            ssum += mv[j];
        }
        float inv = 1.f / ssum;
        float s0 = 0.f, s1 = 0.f;
        #pragma unroll
        for (int j = 0; j < 9; ++j) {
            s0 = fmaf(mv[j], ft0[j], s0);
            s1 = fmaf(mv[j], ft1[j], s1);
        }
        a0[c] = s0 * inv;
        a1[c] = s1 * inv;
    }

    float* ob = out2 + (size_t)(n*2) * UPHW_ + (size_t)(4*h + r) * UPW_ + 4*w;
    *reinterpret_cast<float4*>(ob)         = make_float4(a0[0], a0[1], a0[2], a0[3]);
    *reinterpret_cast<float4*>(ob + UPHW_) = make_float4(a1[0], a1[1], a1[2], a1[3]);
}

extern "C" void kernel_launch(void* const* d_in, const int* in_sizes, int n_in,
                              void* d_out, int out_size, void* d_ws, size_t ws_size,
                              hipStream_t stream) {
    const float* fmap1 = (const float*)d_in[0];
    const float* fmap2 = (const float*)d_in[1];
    const float* flow  = (const float*)d_in[2];
    const float* eo    = (const float*)d_in[3];
    const float* mask  = (const float*)d_in[4];

    float* out  = (float*)d_out;
    float* out0 = out;                            // (N,36,H,W) corr_att_offset
    float* out1 = out + (size_t)N_*36*HW_;        // (N,36,H,W) corr_iter
    float* out2 = out + (size_t)2*N_*36*HW_;      // (N,2,4H,4W) flow_up

    // corr: 8 (n,g) slices * 15x8 tiles of 16x16 = 960 blocks
    corr_kernel<<<960, 256, 0, stream>>>(fmap1, fmap2, flow, eo, out0, out1);
    // upsample: 2n * 4r * 128h * 240w / 256 = 960 blocks
    upsample_kernel<<<960, 256, 0, stream>>>(flow, mask, out2);
}

// Round 6
// 600.348 us; speedup vs baseline: 3.0819x; 1.2217x over previous
//
#include <hip/hip_runtime.h>

#define N_    2
#define W_    240
#define H_    128
#define HW_   (H_*W_)       // 30720
#define UPW_  (4*W_)        // 960
#define UPHW_ ((size_t)(4*H_)*(4*W_))

#define TS    16            // 16x16 pixel tile per block
#define HALO  13
#define WIN   43            // TS + 2*HALO + 1
#define WIN2  (WIN*WIN)     // 1849
#define CH    4             // channels staged per chunk (float4-interleaved)
#define NCHUNK (64/CH)      // 16

// Block = (n,g, 16x16 tile), 256 threads (1 pixel each).
// Stage fmap2 window (43x43, 4 channels interleaved as float4) in LDS;
// 4 bilinear taps per s = 4 x ds_read_b128. Global fallback for outlier flow.
__global__ __launch_bounds__(256) void corr_kernel(
    const float* __restrict__ fmap1, const float* __restrict__ fmap2,
    const float* __restrict__ flow,  const float* __restrict__ eo,
    float* __restrict__ out0, float* __restrict__ out1)
{
    __shared__ float4 win4[WIN2];    // 29584 B

    // XCD swizzle: slice (n,g) = bid&7; tiles row-major within each slice.
    int bid   = blockIdx.x;
    int slice = bid & 7;
    int t     = bid >> 3;            // 0..119
    int tx = t % 15, ty = t / 15;
    int n = slice >> 2, g = slice & 3;

    int lx = threadIdx.x & 15, ly = threadIdx.x >> 4;
    int w = tx*TS + lx, h = ty*TS + ly;
    int pix = h*W_ + w;
    int wx0 = tx*TS - HALO, wy0 = ty*TS - HALO;

    const float* f2g = fmap2 + (size_t)(slice*64)*HW_;
    const float* f1p = fmap1 + (size_t)(slice*64)*HW_ + pix;

    float fx = flow[((size_t)n*2 + 0)*HW_ + pix];
    float fy = flow[((size_t)n*2 + 1)*HW_ + pix];

    // Precompute all 18 sample coordinates (chunk-invariant).
    float xs[18], ys[18];
    #pragma unroll
    for (int s = 0; s < 9; ++s) {
        float ex = eo[((size_t)n*18 + 2*s    )*HW_ + pix];
        float ey = eo[((size_t)n*18 + 2*s + 1)*HW_ + pix];
        xs[s] = (float)w + fx + (float)(s - 4) + ex;
        ys[s] = (float)h + fy + ey;
    }
    #pragma unroll
    for (int j = 0; j < 9; ++j) {
        int dy = j/3 - 1, dx = j%3 - 1;
        int hh = min(max(h + dy, 0), H_-1);
        int ww = min(max(w + dx, 0), W_-1);
        int p2 = hh*W_ + ww;
        xs[9+j] = (float)ww + flow[((size_t)n*2 + 0)*HW_ + p2];
        ys[9+j] = (float)hh + flow[((size_t)n*2 + 1)*HW_ + p2];
    }

    float acc[18];
    #pragma unroll
    for (int s = 0; s < 18; ++s) acc[s] = 0.f;

    for (int ck = 0; ck < NCHUNK; ++ck) {
        int c0 = ck*CH;
        __syncthreads();
        // Stage window: 4 channels interleaved per (row,col) -> one float4.
        {
            const float* pc = f2g + (size_t)c0*HW_;
            for (int it = threadIdx.x; it < WIN2; it += 256) {
                int r = it / WIN;
                int c = it - r*WIN;
                int gy = min(max(wy0 + r, 0), H_-1);
                int gx = min(max(wx0 + c, 0), W_-1);
                const float* p = pc + (size_t)gy*W_ + gx;
                win4[it] = make_float4(p[0], p[HW_], p[(size_t)2*HW_], p[(size_t)3*HW_]);
            }
        }
        __syncthreads();

        float f1v0 = f1p[(size_t)(c0+0)*HW_];
        float f1v1 = f1p[(size_t)(c0+1)*HW_];
        float f1v2 = f1p[(size_t)(c0+2)*HW_];
        float f1v3 = f1p[(size_t)(c0+3)*HW_];

        #pragma unroll
        for (int s = 0; s < 18; ++s) {
            float x = xs[s], y = ys[s];
            float x0f = floorf(x), y0f = floorf(y);
            float fx1 = x - x0f, fy1 = y - y0f;
            float fx0 = 1.f - fx1, fy0 = 1.f - fy1;
            int ix0 = (int)x0f, iy0 = (int)y0f;
            int ix0c = min(max(ix0,   0), W_-1), ix1c = min(max(ix0+1, 0), W_-1);
            int iy0c = min(max(iy0,   0), H_-1), iy1c = min(max(iy0+1, 0), H_-1);
            float vx0 = (ix0   >= 0 && ix0   <= W_-1) ? fx0 : 0.f;
            float vx1 = (ix0+1 >= 0 && ix0+1 <= W_-1) ? fx1 : 0.f;
            float vy0 = (iy0   >= 0 && iy0   <= H_-1) ? fy0 : 0.f;
            float vy1 = (iy0+1 >= 0 && iy0+1 <= H_-1) ? fy1 : 0.f;
            float w00 = vy0*vx0, w01 = vy0*vx1, w10 = vy1*vx0, w11 = vy1*vx1;
            int cx0 = ix0c - wx0, cx1 = ix1c - wx0;
            int cy0 = iy0c - wy0, cy1 = iy1c - wy0;
            bool allin = ((unsigned)cx0 < WIN) & ((unsigned)cx1 < WIN) &
                         ((unsigned)cy0 < WIN) & ((unsigned)cy1 < WIN);
            float a;
            if (allin) {
                int o00 = cy0*WIN + cx0, o01 = cy0*WIN + cx1;
                int o10 = cy1*WIN + cx0, o11 = cy1*WIN + cx1;
                float4 v00 = win4[o00];
                float4 v01 = win4[o01];
                float4 v10 = win4[o10];
                float4 v11 = win4[o11];
                float s0 = w00*v00.x + w01*v01.x + w10*v10.x + w11*v11.x;
                float s1 = w00*v00.y + w01*v01.y + w10*v10.y + w11*v11.y;
                float s2 = w00*v00.z + w01*v01.z + w10*v10.z + w11*v11.z;
                float s3 = w00*v00.w + w01*v01.w + w10*v10.w + w11*v11.w;
                a = f1v0*s0 + f1v1*s1 + f1v2*s2 + f1v3*s3;
            } else {
                int g00 = iy0c*W_ + ix0c, g01 = iy0c*W_ + ix1c;
                int g10 = iy1c*W_ + ix0c, g11 = iy1c*W_ + ix1c;
                a = 0.f;
                const float* gp = f2g + (size_t)c0*HW_;
                float f1vv[4] = {f1v0, f1v1, f1v2, f1v3};
                #pragma unroll
                for (int ci = 0; ci < 4; ++ci) {
                    float smp = w00*gp[g00] + w01*gp[g01]
                              + w10*gp[g10] + w11*gp[g11];
                    a = fmaf(f1vv[ci], smp, a);
                    gp += (size_t)HW_;
                }
            }
            acc[s] += a;
        }
    }

    float* o0 = out0 + ((size_t)(n*36 + g*9))*HW_ + pix;
    float* o1 = out1 + ((size_t)(n*36 + g*9))*HW_ + pix;
    #pragma unroll
    for (int s = 0; s < 9; ++s) o0[(size_t)s*HW_] = acc[s]   * (1.f/64.f);
    #pragma unroll
    for (int j = 0; j < 9; ++j) o1[(size_t)j*HW_] = acc[9+j] * (1.f/64.f);
}

// Thread per (n, r, h, w): computes 4 horizontal sub-pixels (c=0..3),
// stores one contiguous float4 per output channel.
__global__ __launch_bounds__(256) void upsample_kernel(
    const float* __restrict__ flow, const float* __restrict__ mask,
    float* __restrict__ out2)
{
    int t = blockIdx.x * 256 + threadIdx.x;
    int w = t % W_;
    int tmp = t / W_;
    int h = tmp % H_;
    tmp /= H_;
    int r = tmp & 3;
    int n = tmp >> 2;
    int pix = h * W_ + w;

    float ft0[9], ft1[9];
    #pragma unroll
    for (int j = 0; j < 9; ++j) {
        int dy = j/3 - 1, dx = j%3 - 1;
        int hh = h + dy, ww = w + dx;
        bool ok = (hh >= 0) & (hh < H_) & (ww >= 0) & (ww < W_);
        float f0 = 0.f, f1v = 0.f;
        if (ok) {
            int p2 = hh * W_ + ww;
            f0  = flow[((size_t)n*2 + 0)*HW_ + p2];
            f1v = flow[((size_t)n*2 + 1)*HW_ + p2];
        }
        ft0[j] = -4.f * f0;
        ft1[j] = -4.f * f1v;
    }

    float a0[4], a1[4];
    #pragma unroll
    for (int c = 0; c < 4; ++c) {
        const float* mp = mask + ((size_t)n*144 + r*4 + c)*HW_ + pix;
        float mv[9];
        float mx = -1e30f;
        #pragma unroll
        for (int j = 0; j < 9; ++j) {
            mv[j] = mp[(size_t)(j*16)*HW_];
            mx = fmaxf(mx, mv[j]);
        }
        float ssum = 0.f;
        #pragma unroll
        for (int j = 0; j < 9; ++j) {
            mv[j] = __expf(mv[j] - mx);
            ssum += mv[j];
        }
        float inv = 1.f / ssum;
        float s0 = 0.f, s1 = 0.f;
        #pragma unroll
        for (int j = 0; j < 9; ++j) {
            s0 = fmaf(mv[j], ft0[j], s0);
            s1 = fmaf(mv[j], ft1[j], s1);
        }
        a0[c] = s0 * inv;
        a1[c] = s1 * inv;
    }

    float* ob = out2 + (size_t)(n*2) * UPHW_ + (size_t)(4*h + r) * UPW_ + 4*w;
    *reinterpret_cast<float4*>(ob)         = make_float4(a0[0], a0[1], a0[2], a0[3]);
    *reinterpret_cast<float4*>(ob + UPHW_) = make_float4(a1[0], a1[1], a1[2], a1[3]);
}

extern "C" void kernel_launch(void* const* d_in, const int* in_sizes, int n_in,
                              void* d_out, int out_size, void* d_ws, size_t ws_size,
                              hipStream_t stream) {
    const float* fmap1 = (const float*)d_in[0];
    const float* fmap2 = (const float*)d_in[1];
    const float* flow  = (const float*)d_in[2];
    const float* eo    = (const float*)d_in[3];
    const float* mask  = (const float*)d_in[4];

    float* out  = (float*)d_out;
    float* out0 = out;                            // (N,36,H,W) corr_att_offset
    float* out1 = out + (size_t)N_*36*HW_;        // (N,36,H,W) corr_iter
    float* out2 = out + (size_t)2*N_*36*HW_;      // (N,2,4H,4W) flow_up

    // corr: 8 (n,g) slices * 15x8 tiles of 16x16 = 960 blocks
    corr_kernel<<<960, 256, 0, stream>>>(fmap1, fmap2, flow, eo, out0, out1);
    // upsample: 2n * 4r * 128h * 240w / 256 = 960 blocks
    upsample_kernel<<<960, 256, 0, stream>>>(flow, mask, out2);
}